// Round 10
// baseline (1017.609 us; speedup 1.0000x reference)
//
#include <hip/hip_runtime.h>
#include <math.h>

#define B 32
#define N 16384
#define M 128
#define D 1024
#define L 390   // 3*M+6
#define EPSF 1e-16f

// ws layout (floats):
//   [O_OFF,  O_OFF+B*L)   o = emb@W + b
//   [S1_OFF, +B)          sum exp(z)   (atomic; zeroed by k1)
//   [S2_OFF, +B)          sum w_sh     (atomic; zeroed by k1)
//   [Z_OFF,  +B*N)        u = exp(beta*sim)
// Per-batch params are recomputed locally per block from o.
// k3 is a pure S2 reduction; k4 recomputes w per thread (identical
// arithmetic -> identical values).
#define O_OFF  0
#define S1_OFF (B*L)
#define S2_OFF (S1_OFF + B)
#define Z_OFF  (S2_OFF + B)

typedef float fvec4 __attribute__((ext_vector_type(4)));

__device__ __forceinline__ float softplusf(float x) {
    return x > 20.f ? x : log1pf(expf(x));
}
__device__ __forceinline__ float sigmoidf(float x) {
    return 1.f / (1.f + expf(-x));
}

// K1: o[b, l0:l0+64] = emb[b,:] @ W[:, l0:l0+64] + bias.  grid(7, B), 256 thr.
// Block x==0 also zeroes the S1/S2 accumulators for its batch.
__global__ __launch_bounds__(256) void k1_gemm(const float* __restrict__ emb,
                                               const float* __restrict__ W,
                                               const float* __restrict__ bias,
                                               float* __restrict__ ws) {
    __shared__ float embS[D];
    __shared__ float red[4][64];
    const int l0 = blockIdx.x * 64;
    const int b  = blockIdx.y;
    const int t  = threadIdx.x;
    for (int i = t; i < D; i += 256) embS[i] = emb[b * D + i];
    if (blockIdx.x == 0 && t == 0) {
        ws[S1_OFF + b] = 0.f;
        ws[S2_OFF + b] = 0.f;
    }
    __syncthreads();
    const int li = t & 63;
    const int q  = t >> 6;          // 4-way split of the D dimension
    const int l  = l0 + li;
    float partial = 0.f;
    if (l < L) {
        const float* wp = W + (size_t)(q * 256) * L + l;
        #pragma unroll 8
        for (int d = 0; d < 256; ++d) partial += embS[q * 256 + d] * wp[(size_t)d * L];
    }
    red[q][li] = partial;
    __syncthreads();
    if (t < 64 && l0 + t < L) {
        float o = red[0][t] + red[1][t] + red[2][t] + red[3][t] + bias[l0 + t];
        ws[O_OFF + b * L + l0 + t] = o;
    }
}

// K2: u[b,n] = exp(beta*cos_sim(mem[b,n,:],k)); atomic S1 += sum u.
// ROW-PER-LANE (proven fastest, R3/R4/R7): each lane owns one full row
// (32 x float4 independent sequential loads, k broadcast from LDS).
// knorm/beta computed locally per block. grid(N/256, B), 256 thr.
__global__ __launch_bounds__(256) void k2_sim(const float* __restrict__ mem,
                                              float* __restrict__ ws) {
    const int b = blockIdx.y;
    const int t = threadIdx.x;
    const int n = blockIdx.x * 256 + t;
    const int wave = t >> 6, lane = t & 63;
    __shared__ float kS[M];
    __shared__ float par[2];        // {knorm, beta}
    __shared__ float acc[4];
    const float* o = ws + O_OFF + b * L;
    if (t < M) kS[t] = o[t];
    __syncthreads();
    if (t < M) {                               // local ||k||
        float kv = kS[t];
        float sq = kv * kv;
        #pragma unroll
        for (int off = 32; off >= 1; off >>= 1) sq += __shfl_xor(sq, off, 64);
        if (lane == 0) acc[t >> 6] = sq;
    }
    __syncthreads();
    if (t == 0) {
        par[0] = sqrtf(acc[0] + acc[1]);
        par[1] = softplusf(o[M]);
    }
    __syncthreads();
    const float knorm = par[0], beta = par[1];
    const float* mp = mem + ((size_t)b * N + n) * M;

    float dot = 0.f, sq = 0.f;
    #pragma unroll 16
    for (int j = 0; j < M / 4; ++j) {
        const fvec4 mv = *(const fvec4*)(mp + j * 4);
        const fvec4 kv = *(const fvec4*)&kS[j * 4];     // LDS broadcast
        dot = fmaf(mv.x, kv.x, dot); dot = fmaf(mv.y, kv.y, dot);
        dot = fmaf(mv.z, kv.z, dot); dot = fmaf(mv.w, kv.w, dot);
        sq  = fmaf(mv.x, mv.x, sq);  sq  = fmaf(mv.y, mv.y, sq);
        sq  = fmaf(mv.z, mv.z, sq);  sq  = fmaf(mv.w, mv.w, sq);
    }
    const float sim = dot / (sqrtf(sq) * knorm + EPSF);
    const float uu  = expf(beta * sim);
    ws[Z_OFF + (size_t)b * N + n] = uu;        // fully coalesced store

    float r = uu;                              // block reduction -> S1
    #pragma unroll
    for (int off = 32; off >= 1; off >>= 1) r += __shfl_xor(r, off, 64);
    if (lane == 0) acc[wave] = r;
    __syncthreads();
    if (t == 0) atomicAdd(ws + S1_OFF + b, acc[0] + acc[1] + acc[2] + acc[3]);
}

// K3: PURE S2 reduction: S2 += sum_n (s0*wg(n-1)+s1*wg(n)+s2*wg(n+1))^gamma.
// No w_sh store (k4 recomputes identically). grid(N/256, B), 256 thr.
__global__ __launch_bounds__(256) void k3_s2(const float* __restrict__ w_prev,
                                             float* __restrict__ ws) {
    const int b = blockIdx.y;
    const int n = blockIdx.x * 256 + threadIdx.x;
    __shared__ float par[6];        // {g, s0, s1, s2, gamma, invS1}
    if (threadIdx.x == 0) {
        const float* o = ws + O_OFF + b * L;
        par[0] = sigmoidf(o[M + 1]);
        float x0 = o[M + 2], x1 = o[M + 3], x2 = o[M + 4];
        float mx = fmaxf(x0, fmaxf(x1, x2));
        float e0 = expf(x0 - mx), e1 = expf(x1 - mx), e2 = expf(x2 - mx);
        float inv = 1.f / (e0 + e1 + e2);
        par[1] = e0 * inv; par[2] = e1 * inv; par[3] = e2 * inv;
        par[4] = 1.f + softplusf(o[M + 5]);
        par[5] = 1.f / ws[S1_OFF + b];
    }
    __syncthreads();
    const float g = par[0], s0 = par[1], s1 = par[2], s2 = par[3];
    const float gamma = par[4], invS1 = par[5];
    const float* u  = ws + Z_OFF + (size_t)b * N;
    const float* wp = w_prev + (size_t)b * N;
    const int nm = (n == 0)     ? N - 1 : n - 1;
    const int np = (n == N - 1) ? 0     : n + 1;
    const float gm1 = 1.f - g;
    const float gi  = g * invS1;
    const float wgm = gi * u[nm] + gm1 * wp[nm];
    const float wg0 = gi * u[n ] + gm1 * wp[n ];
    const float wgp = gi * u[np] + gm1 * wp[np];
    const float wt  = s0 * wgm + s1 * wg0 + s2 * wgp;
    const float v = powf(wt, gamma);
    float r = v;
    #pragma unroll
    for (int off = 32; off >= 1; off >>= 1) r += __shfl_xor(r, off, 64);
    __shared__ float acc[4];
    if ((threadIdx.x & 63) == 0) acc[threadIdx.x >> 6] = r;
    __syncthreads();
    if (threadIdx.x == 0) atomicAdd(ws + S2_OFF + b, acc[0] + acc[1] + acc[2] + acc[3]);
}

// K4: ROW-PER-LANE (round 10) -- the layout that won k2 by 15-25us, now
// applied to k4's 2x-bigger stream. 256 threads = 256 rows/block; each
// thread computes its OWN row's w (k3 arithmetic, all threads parallel ->
// no t<64 serialization, no wS LDS round-trip, coalesced 256-wide w store)
// then streams its row: 32 sequential fvec4 loads from mem, fma against
// LDS-broadcast e/a, NT stores (R8: plain stores cost +10us via L3
// eviction of mem). Groups of 4 loads before 4 stores keep loads in
// flight. Reversed traversal for L3 LRU. grid(N/256, B), 256 thr.
__global__ __launch_bounds__(256) void k4_write(const float* __restrict__ mem,
                                                const float* __restrict__ w_prev,
                                                const float* __restrict__ ws,
                                                float* __restrict__ out) {
    const int b  = blockIdx.y;
    const int n0 = (gridDim.x - 1 - blockIdx.x) * 256;   // reversed traversal
    const int t  = threadIdx.x;
    __shared__ float eS[M], aS[M];
    __shared__ float par[8];
    const float* o = ws + O_OFF + b * L;
    if (t < M) {
        eS[t] = sigmoidf(o[M + 6 + t]);
        aS[t] = o[2 * M + 6 + t];
    }
    if (t == 0) {
        par[0] = sigmoidf(o[M + 1]);
        float x0 = o[M + 2], x1 = o[M + 3], x2 = o[M + 4];
        float mx = fmaxf(x0, fmaxf(x1, x2));
        float e0 = expf(x0 - mx), e1 = expf(x1 - mx), e2 = expf(x2 - mx);
        float inv = 1.f / (e0 + e1 + e2);
        par[1] = e0 * inv; par[2] = e1 * inv; par[3] = e2 * inv;
        par[4] = 1.f + softplusf(o[M + 5]);
        par[5] = 1.f / ws[S1_OFF + b];
        par[6] = 1.f / (ws[S2_OFF + b] + EPSF);
    }
    __syncthreads();

    // per-thread w for this thread's own row (k3 arithmetic -> same values)
    const int n = n0 + t;
    {
        const float g = par[0], s0 = par[1], s1v = par[2], s2v = par[3];
        const float gamma = par[4], invS1 = par[5], invS2 = par[6];
        const float gi = g * invS1, gm1 = 1.f - g;
        const float* u  = ws + Z_OFF + (size_t)b * N;
        const float* wp = w_prev + (size_t)b * N;
        const int nm = (n == 0)     ? N - 1 : n - 1;
        const int np = (n == N - 1) ? 0     : n + 1;
        const float wgm = gi * u[nm] + gm1 * wp[nm];
        const float wg0 = gi * u[n ] + gm1 * wp[n ];
        const float wgp = gi * u[np] + gm1 * wp[np];
        const float wt  = s0 * wgm + s1v * wg0 + s2v * wgp;
        const float w   = powf(wt, gamma) * invS2;
        out[(size_t)b * N + n] = w;            // coalesced 256-wide w store

        // stream own row sequentially (row-per-lane pattern)
        const size_t ro = ((size_t)b * N + n) * M;
        const float* src = mem + ro;
        float*       dst = out + (size_t)B * N + ro;
        #pragma unroll
        for (int j0 = 0; j0 < M / 4; j0 += 4) {
            const fvec4 v0 = *(const fvec4*)(src + (j0 + 0) * 4);
            const fvec4 v1 = *(const fvec4*)(src + (j0 + 1) * 4);
            const fvec4 v2 = *(const fvec4*)(src + (j0 + 2) * 4);
            const fvec4 v3 = *(const fvec4*)(src + (j0 + 3) * 4);
            const fvec4 e0 = *(const fvec4*)&eS[(j0 + 0) * 4];
            const fvec4 e1 = *(const fvec4*)&eS[(j0 + 1) * 4];
            const fvec4 e2 = *(const fvec4*)&eS[(j0 + 2) * 4];
            const fvec4 e3 = *(const fvec4*)&eS[(j0 + 3) * 4];
            const fvec4 a0 = *(const fvec4*)&aS[(j0 + 0) * 4];
            const fvec4 a1 = *(const fvec4*)&aS[(j0 + 1) * 4];
            const fvec4 a2 = *(const fvec4*)&aS[(j0 + 2) * 4];
            const fvec4 a3 = *(const fvec4*)&aS[(j0 + 3) * 4];
            fvec4 r0, r1, r2, r3;
            r0.x = fmaf(v0.x, fmaf(-w, e0.x, 1.f), w * a0.x);
            r0.y = fmaf(v0.y, fmaf(-w, e0.y, 1.f), w * a0.y);
            r0.z = fmaf(v0.z, fmaf(-w, e0.z, 1.f), w * a0.z);
            r0.w = fmaf(v0.w, fmaf(-w, e0.w, 1.f), w * a0.w);
            r1.x = fmaf(v1.x, fmaf(-w, e1.x, 1.f), w * a1.x);
            r1.y = fmaf(v1.y, fmaf(-w, e1.y, 1.f), w * a1.y);
            r1.z = fmaf(v1.z, fmaf(-w, e1.z, 1.f), w * a1.z);
            r1.w = fmaf(v1.w, fmaf(-w, e1.w, 1.f), w * a1.w);
            r2.x = fmaf(v2.x, fmaf(-w, e2.x, 1.f), w * a2.x);
            r2.y = fmaf(v2.y, fmaf(-w, e2.y, 1.f), w * a2.y);
            r2.z = fmaf(v2.z, fmaf(-w, e2.z, 1.f), w * a2.z);
            r2.w = fmaf(v2.w, fmaf(-w, e2.w, 1.f), w * a2.w);
            r3.x = fmaf(v3.x, fmaf(-w, e3.x, 1.f), w * a3.x);
            r3.y = fmaf(v3.y, fmaf(-w, e3.y, 1.f), w * a3.y);
            r3.z = fmaf(v3.z, fmaf(-w, e3.z, 1.f), w * a3.z);
            r3.w = fmaf(v3.w, fmaf(-w, e3.w, 1.f), w * a3.w);
            __builtin_nontemporal_store(r0, (fvec4*)(dst + (j0 + 0) * 4));
            __builtin_nontemporal_store(r1, (fvec4*)(dst + (j0 + 1) * 4));
            __builtin_nontemporal_store(r2, (fvec4*)(dst + (j0 + 2) * 4));
            __builtin_nontemporal_store(r3, (fvec4*)(dst + (j0 + 3) * 4));
        }
    }
}

extern "C" void kernel_launch(void* const* d_in, const int* in_sizes, int n_in,
                              void* d_out, int out_size, void* d_ws, size_t ws_size,
                              hipStream_t stream) {
    const float* emb    = (const float*)d_in[0];
    const float* w_prev = (const float*)d_in[1];
    const float* mem    = (const float*)d_in[2];
    const float* W      = (const float*)d_in[3];
    const float* bias   = (const float*)d_in[4];
    float* ws  = (float*)d_ws;    // needs (B*L + 2*B + B*N)*4 ≈ 2.15 MB
    float* out = (float*)d_out;

    k1_gemm <<<dim3(7, B),       256, 0, stream>>>(emb, W, bias, ws);
    k2_sim  <<<dim3(N / 256, B), 256, 0, stream>>>(mem, ws);
    k3_s2   <<<dim3(N / 256, B), 256, 0, stream>>>(w_prev, ws);
    k4_write<<<dim3(N / 256, B), 256, 0, stream>>>(mem, w_prev, ws, out);
}

// Round 11
// 535.852 us; speedup vs baseline: 1.8990x; 1.8990x over previous
//
#include <hip/hip_runtime.h>
#include <math.h>

#define B 32
#define N 16384
#define M 128
#define D 1024
#define L 390   // 3*M+6
#define EPSF 1e-16f

// ws layout (floats):
//   [O_OFF,  O_OFF+B*L)   o = emb@W + b
//   [S1_OFF, +B)          sum exp(z)   (atomic; zeroed by k1)
//   [S2_OFF, +B)          sum w_sh     (atomic; zeroed by k1)
//   [Z_OFF,  +B*N)        u = exp(beta*sim)
// Per-batch params are recomputed locally per block from o.
// w_sh does not round-trip through `out`: k3 is a pure S2 reduction and
// k4 recomputes w per block (identical arithmetic -> identical values).
//
// Session ledger (all A/B'd on MI355X):
//  - k2 ROW-PER-LANE beats 16-lane-group by ~15us (R6/R7).
//  - k4 GROUPED (wave-coalesced 1KB/instr) is mandatory: row-per-lane NT
//    writes fragment 64B sectors -> 3.3x WRITE_SIZE inflation (R10 PMC).
//  - k4 NT stores beat plain by ~10us (R8: plain evicts L3-resident mem).
//  - k4 plain loads (L3-hot from k2) == NT loads (R4); explicit load
//    preload == compiler schedule (R9).
//  - Cooperative fusion dead: gg.sync() ~110us each on 8 XCDs (R2/R5).
#define O_OFF  0
#define S1_OFF (B*L)
#define S2_OFF (S1_OFF + B)
#define Z_OFF  (S2_OFF + B)

typedef float fvec4 __attribute__((ext_vector_type(4)));

__device__ __forceinline__ float softplusf(float x) {
    return x > 20.f ? x : log1pf(expf(x));
}
__device__ __forceinline__ float sigmoidf(float x) {
    return 1.f / (1.f + expf(-x));
}

// K1: o[b, l0:l0+64] = emb[b,:] @ W[:, l0:l0+64] + bias.  grid(7, B), 256 thr.
// Block x==0 also zeroes the S1/S2 accumulators for its batch.
__global__ __launch_bounds__(256) void k1_gemm(const float* __restrict__ emb,
                                               const float* __restrict__ W,
                                               const float* __restrict__ bias,
                                               float* __restrict__ ws) {
    __shared__ float embS[D];
    __shared__ float red[4][64];
    const int l0 = blockIdx.x * 64;
    const int b  = blockIdx.y;
    const int t  = threadIdx.x;
    for (int i = t; i < D; i += 256) embS[i] = emb[b * D + i];
    if (blockIdx.x == 0 && t == 0) {
        ws[S1_OFF + b] = 0.f;
        ws[S2_OFF + b] = 0.f;
    }
    __syncthreads();
    const int li = t & 63;
    const int q  = t >> 6;          // 4-way split of the D dimension
    const int l  = l0 + li;
    float partial = 0.f;
    if (l < L) {
        const float* wp = W + (size_t)(q * 256) * L + l;
        #pragma unroll 8
        for (int d = 0; d < 256; ++d) partial += embS[q * 256 + d] * wp[(size_t)d * L];
    }
    red[q][li] = partial;
    __syncthreads();
    if (t < 64 && l0 + t < L) {
        float o = red[0][t] + red[1][t] + red[2][t] + red[3][t] + bias[l0 + t];
        ws[O_OFF + b * L + l0 + t] = o;
    }
}

// K2: u[b,n] = exp(beta*cos_sim(mem[b,n,:],k)); atomic S1 += sum u.
// ROW-PER-LANE (proven fastest, R3/R4/R7): each lane owns one full row
// (32 x float4 independent sequential loads, k broadcast from LDS).
// knorm/beta computed locally per block. grid(N/256, B), 256 thr.
__global__ __launch_bounds__(256) void k2_sim(const float* __restrict__ mem,
                                              float* __restrict__ ws) {
    const int b = blockIdx.y;
    const int t = threadIdx.x;
    const int n = blockIdx.x * 256 + t;
    const int wave = t >> 6, lane = t & 63;
    __shared__ float kS[M];
    __shared__ float par[2];        // {knorm, beta}
    __shared__ float acc[4];
    const float* o = ws + O_OFF + b * L;
    if (t < M) kS[t] = o[t];
    __syncthreads();
    if (t < M) {                               // local ||k||
        float kv = kS[t];
        float sq = kv * kv;
        #pragma unroll
        for (int off = 32; off >= 1; off >>= 1) sq += __shfl_xor(sq, off, 64);
        if (lane == 0) acc[t >> 6] = sq;
    }
    __syncthreads();
    if (t == 0) {
        par[0] = sqrtf(acc[0] + acc[1]);
        par[1] = softplusf(o[M]);
    }
    __syncthreads();
    const float knorm = par[0], beta = par[1];
    const float* mp = mem + ((size_t)b * N + n) * M;

    float dot = 0.f, sq = 0.f;
    #pragma unroll 16
    for (int j = 0; j < M / 4; ++j) {
        const fvec4 mv = *(const fvec4*)(mp + j * 4);
        const fvec4 kv = *(const fvec4*)&kS[j * 4];     // LDS broadcast
        dot = fmaf(mv.x, kv.x, dot); dot = fmaf(mv.y, kv.y, dot);
        dot = fmaf(mv.z, kv.z, dot); dot = fmaf(mv.w, kv.w, dot);
        sq  = fmaf(mv.x, mv.x, sq);  sq  = fmaf(mv.y, mv.y, sq);
        sq  = fmaf(mv.z, mv.z, sq);  sq  = fmaf(mv.w, mv.w, sq);
    }
    const float sim = dot / (sqrtf(sq) * knorm + EPSF);
    const float uu  = expf(beta * sim);
    ws[Z_OFF + (size_t)b * N + n] = uu;        // fully coalesced store

    float r = uu;                              // block reduction -> S1
    #pragma unroll
    for (int off = 32; off >= 1; off >>= 1) r += __shfl_xor(r, off, 64);
    if (lane == 0) acc[wave] = r;
    __syncthreads();
    if (t == 0) atomicAdd(ws + S1_OFF + b, acc[0] + acc[1] + acc[2] + acc[3]);
}

// K3: PURE S2 reduction: S2 += sum_n (s0*wg(n-1)+s1*wg(n)+s2*wg(n+1))^gamma.
// No w_sh store (k4 recomputes identically). grid(N/256, B), 256 thr.
__global__ __launch_bounds__(256) void k3_s2(const float* __restrict__ w_prev,
                                             float* __restrict__ ws) {
    const int b = blockIdx.y;
    const int n = blockIdx.x * 256 + threadIdx.x;
    __shared__ float par[6];        // {g, s0, s1, s2, gamma, invS1}
    if (threadIdx.x == 0) {
        const float* o = ws + O_OFF + b * L;
        par[0] = sigmoidf(o[M + 1]);
        float x0 = o[M + 2], x1 = o[M + 3], x2 = o[M + 4];
        float mx = fmaxf(x0, fmaxf(x1, x2));
        float e0 = expf(x0 - mx), e1 = expf(x1 - mx), e2 = expf(x2 - mx);
        float inv = 1.f / (e0 + e1 + e2);
        par[1] = e0 * inv; par[2] = e1 * inv; par[3] = e2 * inv;
        par[4] = 1.f + softplusf(o[M + 5]);
        par[5] = 1.f / ws[S1_OFF + b];
    }
    __syncthreads();
    const float g = par[0], s0 = par[1], s1 = par[2], s2 = par[3];
    const float gamma = par[4], invS1 = par[5];
    const float* u  = ws + Z_OFF + (size_t)b * N;
    const float* wp = w_prev + (size_t)b * N;
    const int nm = (n == 0)     ? N - 1 : n - 1;
    const int np = (n == N - 1) ? 0     : n + 1;
    const float gm1 = 1.f - g;
    const float gi  = g * invS1;
    const float wgm = gi * u[nm] + gm1 * wp[nm];
    const float wg0 = gi * u[n ] + gm1 * wp[n ];
    const float wgp = gi * u[np] + gm1 * wp[np];
    const float wt  = s0 * wgm + s1 * wg0 + s2 * wgp;
    const float v = powf(wt, gamma);
    float r = v;
    #pragma unroll
    for (int off = 32; off >= 1; off >>= 1) r += __shfl_xor(r, off, 64);
    __shared__ float acc[4];
    if ((threadIdx.x & 63) == 0) acc[threadIdx.x >> 6] = r;
    __syncthreads();
    if (threadIdx.x == 0) atomicAdd(ws + S2_OFF + b, acc[0] + acc[1] + acc[2] + acc[3]);
}

// K4: GROUPED layout (proven, R7 = session best): per-block prologue
// recomputes w for its 64 rows into LDS + one coalesced w store; main loop
// streams with 32 lanes spanning each row -> every NT store instruction
// writes 1KB contiguous (full 64B sectors; row-per-lane fragments sectors,
// R10: 3.3x WRITE_SIZE). Plain loads (mem L3-hot from k2), NT stores
// (R8: plain stores evict mem), reversed traversal for L3 LRU.
// grid(N/64, B), 256 thr = 4 waves, 16 rows/wave.
__global__ __launch_bounds__(256) void k4_write(const float* __restrict__ mem,
                                                const float* __restrict__ w_prev,
                                                const float* __restrict__ ws,
                                                float* __restrict__ out) {
    const int b    = blockIdx.y;
    const int n0   = (gridDim.x - 1 - blockIdx.x) * 64;   // reversed traversal
    const int t    = threadIdx.x;
    const int wave = t >> 6, lane = t & 63;
    __shared__ float eS[M], aS[M], wS[64];
    __shared__ float par[8];
    const float* o = ws + O_OFF + b * L;
    if (t < M) {
        eS[t] = sigmoidf(o[M + 6 + t]);
        aS[t] = o[2 * M + 6 + t];
    }
    if (t == 0) {
        par[0] = sigmoidf(o[M + 1]);
        float x0 = o[M + 2], x1 = o[M + 3], x2 = o[M + 4];
        float mx = fmaxf(x0, fmaxf(x1, x2));
        float e0 = expf(x0 - mx), e1 = expf(x1 - mx), e2 = expf(x2 - mx);
        float inv = 1.f / (e0 + e1 + e2);
        par[1] = e0 * inv; par[2] = e1 * inv; par[3] = e2 * inv;
        par[4] = 1.f + softplusf(o[M + 5]);
        par[5] = 1.f / ws[S1_OFF + b];
        par[6] = 1.f / (ws[S2_OFF + b] + EPSF);
    }
    __syncthreads();
    if (t < 64) {                              // w for this block's 64 rows
        const int n  = n0 + t;
        const float g = par[0], s0 = par[1], s1v = par[2], s2v = par[3];
        const float gamma = par[4], invS1 = par[5], invS2 = par[6];
        const float gi = g * invS1, gm1 = 1.f - g;
        const float* u  = ws + Z_OFF + (size_t)b * N;
        const float* wp = w_prev + (size_t)b * N;
        const int nm = (n == 0)     ? N - 1 : n - 1;
        const int np = (n == N - 1) ? 0     : n + 1;
        const float wgm = gi * u[nm] + gm1 * wp[nm];
        const float wg0 = gi * u[n ] + gm1 * wp[n ];
        const float wgp = gi * u[np] + gm1 * wp[np];
        const float wt  = s0 * wgm + s1v * wg0 + s2v * wgp;
        const float wv  = powf(wt, gamma) * invS2;
        wS[t] = wv;
        out[(size_t)b * N + n] = wv;           // coalesced 64-lane w store
    }
    __syncthreads();
    float* m_out = out + (size_t)B * N;
    const int col  = (lane & 31) * 4;
    const int half = lane >> 5;
    const fvec4 ev = *(const fvec4*)&eS[col];
    const fvec4 av = *(const fvec4*)&aS[col];
    #pragma unroll
    for (int it = 0; it < 8; ++it) {
        const int loc = wave * 16 + it * 2 + half;
        const int n   = n0 + loc;
        const float w = wS[loc];               // LDS broadcast
        const size_t idx = ((size_t)b * N + n) * M + col;
        const fvec4 mv = *(const fvec4*)(mem + idx);   // L3-hot from k2
        fvec4 r;
        r.x = fmaf(mv.x, fmaf(-w, ev.x, 1.f), w * av.x);
        r.y = fmaf(mv.y, fmaf(-w, ev.y, 1.f), w * av.y);
        r.z = fmaf(mv.z, fmaf(-w, ev.z, 1.f), w * av.z);
        r.w = fmaf(mv.w, fmaf(-w, ev.w, 1.f), w * av.w);
        __builtin_nontemporal_store(r, (fvec4*)(m_out + idx));
    }
}

extern "C" void kernel_launch(void* const* d_in, const int* in_sizes, int n_in,
                              void* d_out, int out_size, void* d_ws, size_t ws_size,
                              hipStream_t stream) {
    const float* emb    = (const float*)d_in[0];
    const float* w_prev = (const float*)d_in[1];
    const float* mem    = (const float*)d_in[2];
    const float* W      = (const float*)d_in[3];
    const float* bias   = (const float*)d_in[4];
    float* ws  = (float*)d_ws;    // needs (B*L + 2*B + B*N)*4 ≈ 2.15 MB
    float* out = (float*)d_out;

    k1_gemm <<<dim3(7, B),       256, 0, stream>>>(emb, W, bias, ws);
    k2_sim  <<<dim3(N / 256, B), 256, 0, stream>>>(mem, ws);
    k3_s2   <<<dim3(N / 256, B), 256, 0, stream>>>(w_prev, ws);
    k4_write<<<dim3(N / 64, B),  256, 0, stream>>>(mem, w_prev, ws, out);
}